// Round 17
// baseline (48.162 us; speedup 1.0000x reference)
//
#include <hip/hip_runtime.h>

// Chamfer (bidirectional 1-NN mean of squared distances), two [16384,3] fp32 clouds.
// Round-17: occupancy lever. R15 direct read: Occupancy 35%, VGPR=64, inner loop
// latency-limited (marginal 13.1us vs ~5.5us overlapped floor). VGPR=64 permits
// 8 waves/SIMD; at NBSPLIT=16 we only offered 4 blocks/CU. Single change vs R16:
// NBSPLIT 16->32 => 2048 blocks = 8 blocks/CU = 32 waves/CU (occupancy cap).
// Col-partial store traffic invariant (disjoint BSWEEP slices, 4MB total).
// Everything else identical to R16 (verified absmax 0.0).
//
// MFMA formulation (one v_mfma_f32_32x32x16_f16 per 32x32 distance tile):
//   x = xh + xl (split fp16). K slots:
//     0..2 A=-2a_hi B=b_hi | 3..5 A=-2a_hi B=b_lo | 6..8 A=-2a_lo B=b_hi
//     9,10 A={a2_hi,a2_lo} B={1,1} | 11,12 A={1,1} B={b2_hi,b2_lo} | 13..15 zero
//   => D[i][j] = a2 + b2 - 2 a.b + O(3e-3), fp32 accumulators.
// C/D layout (verified): col=lane&31, row=(reg&3)+8*(reg>>2)+4*(lane>>5).

typedef _Float16 half8 __attribute__((ext_vector_type(8)));
typedef float floatx16 __attribute__((ext_vector_type(16)));

#define NPTS 16384
#define BLOCK 256
#define WAVES 4
#define TILE 32
#define ROWSW (2 * TILE)              // 64 A-rows per wave (2 fragments)
#define APB (WAVES * ROWSW)           // 256 A-points per block
#define NXB (NPTS / APB)              // 64 x-blocks (= col-partial slabs)
#define NBSPLIT 32
#define BSWEEP (NPTS / NBSPLIT)       // 512 B-points per block
#define NTILES (BSWEEP / TILE)        // 16 B-tiles per block

union H8 { _Float16 h[8]; uint4 u; };

// P0 -> A-frags, P1 -> B-frags (32 B/point); init row-min array (NPTS u32).
__global__ __launch_bounds__(256) void prep_kernel(
    const float* __restrict__ P0, const float* __restrict__ P1,
    uint4* __restrict__ Ap, uint4* __restrict__ Bp,
    unsigned* __restrict__ dmin_row)
{
    const int i = blockIdx.x * 256 + threadIdx.x;      // 0..2*NPTS-1
    const bool isA = (i < NPTS);
    if (isA) dmin_row[i] = 0x7F7F7F7Fu;                // 3.39e38 > any real distance

    const float* P = isA ? P0 : P1;
    const int k = isA ? i : i - NPTS;
    const float x = P[k * 3 + 0], y = P[k * 3 + 1], z = P[k * 3 + 2];
    const float q2 = x * x + y * y + z * z;

    const _Float16 xh = (_Float16)x; const float xl = x - (float)xh;
    const _Float16 yh = (_Float16)y; const float yl = y - (float)yh;
    const _Float16 zh = (_Float16)z; const float zl = z - (float)zh;
    const _Float16 qh = (_Float16)q2; const float ql = q2 - (float)qh;
    const _Float16 one = (_Float16)1.0f, zero = (_Float16)0.0f;

    if (isA) {
        H8 a0, a1;
        a0.h[0] = (_Float16)(-2.0f * (float)xh);
        a0.h[1] = (_Float16)(-2.0f * (float)yh);
        a0.h[2] = (_Float16)(-2.0f * (float)zh);
        a0.h[3] = a0.h[0]; a0.h[4] = a0.h[1]; a0.h[5] = a0.h[2];
        a0.h[6] = (_Float16)(-2.0f * xl);
        a0.h[7] = (_Float16)(-2.0f * yl);
        a1.h[0] = (_Float16)(-2.0f * zl);
        a1.h[1] = qh; a1.h[2] = (_Float16)ql;
        a1.h[3] = one; a1.h[4] = one;
        a1.h[5] = zero; a1.h[6] = zero; a1.h[7] = zero;
        Ap[(size_t)k * 2 + 0] = a0.u; Ap[(size_t)k * 2 + 1] = a1.u;
    } else {
        H8 b0, b1;
        b0.h[0] = xh; b0.h[1] = yh; b0.h[2] = zh;
        b0.h[3] = (_Float16)xl; b0.h[4] = (_Float16)yl; b0.h[5] = (_Float16)zl;
        b0.h[6] = xh; b0.h[7] = yh;
        b1.h[0] = zh; b1.h[1] = one; b1.h[2] = one;
        b1.h[3] = qh; b1.h[4] = (_Float16)ql;
        b1.h[5] = zero; b1.h[6] = zero; b1.h[7] = zero;
        Bp[(size_t)k * 2 + 0] = b0.u; Bp[(size_t)k * 2 + 1] = b1.u;
    }
}

#define MF(afx, bf) __builtin_amdgcn_mfma_f32_32x32x16_f16((afx), (bf), ZC, 0, 0, 0)

__global__ __launch_bounds__(BLOCK, 4) void chamfer_mfma(
    const uint4* __restrict__ Ap, const uint4* __restrict__ Bp,
    unsigned* __restrict__ dmin_row, unsigned* __restrict__ colpart)
{
    __shared__ unsigned scmin[BSWEEP];   // block-level col-min accumulator (2 KB)

    const int tid  = threadIdx.x;
    const int lane = tid & 63;
    const int wid  = tid >> 6;
    const int half = lane >> 5;
    const int lj   = lane & 31;

    for (int i = tid; i < BSWEEP; i += BLOCK) scmin[i] = 0x7F7F7F7Fu;
    __syncthreads();

    const int arow0 = blockIdx.x * APB + wid * ROWSW;

    const half8 af0 = *reinterpret_cast<const half8*>(
        &Ap[((size_t)(arow0 + lj)) * 2 + half]);
    const half8 af1 = *reinterpret_cast<const half8*>(
        &Ap[((size_t)(arow0 + 32 + lj)) * 2 + half]);

    const floatx16 ZC = (floatx16)(0.0f);

    float rmin0[16], rmin1[16];
#pragma unroll
    for (int r = 0; r < 16; ++r) { rmin0[r] = 3.0e38f; rmin1[r] = 3.0e38f; }

    const int bbase = blockIdx.y * BSWEEP;
    const uint4* Bc = Bp + (size_t)bbase * 2;

    // Inner loop identical to R14/R16 (verified): per B-tile, 2 MFMAs, row mins
    // into registers, col tree + cross-half shuffle + LDS atomic. B from L2.
#pragma unroll 2
    for (int t = 0; t < NTILES; ++t) {
        const half8 bf = *reinterpret_cast<const half8*>(
            &Bc[(size_t)(t * TILE + lj) * 2 + half]);
        const floatx16 dA = MF(af0, bf);
        const floatx16 dB = MF(af1, bf);
#pragma unroll
        for (int r = 0; r < 16; ++r) {
            rmin0[r] = fminf(dA[r], rmin0[r]);
            rmin1[r] = fminf(dB[r], rmin1[r]);
        }
        float c = fminf(dA[0], dB[0]);
#pragma unroll
        for (int r = 1; r < 16; ++r) c = fminf(fminf(dA[r], dB[r]), c);
        c = fminf(c, __shfl_xor(c, 32, 64));
        if (lane < 32)
            atomicMin(&scmin[t * TILE + lj], __float_as_uint(fmaxf(c, 0.0f)));
    }

    // Row-side: butterfly + global atomicMin (16K atomics total, cheap).
#pragma unroll
    for (int r = 0; r < 16; ++r) {
        float v0 = rmin0[r];
        v0 = fminf(v0, __shfl_xor(v0, 1, 32));
        v0 = fminf(v0, __shfl_xor(v0, 2, 32));
        v0 = fminf(v0, __shfl_xor(v0, 4, 32));
        v0 = fminf(v0, __shfl_xor(v0, 8, 32));
        v0 = fminf(v0, __shfl_xor(v0, 16, 32));
        rmin0[r] = v0;
        float v1 = rmin1[r];
        v1 = fminf(v1, __shfl_xor(v1, 1, 32));
        v1 = fminf(v1, __shfl_xor(v1, 2, 32));
        v1 = fminf(v1, __shfl_xor(v1, 4, 32));
        v1 = fminf(v1, __shfl_xor(v1, 8, 32));
        v1 = fminf(v1, __shfl_xor(v1, 16, 32));
        rmin1[r] = v1;
    }
    if (lj == 0) {
#pragma unroll
        for (int r = 0; r < 16; ++r) {
            const int row = (r & 3) + 8 * (r >> 2) + 4 * half;
            atomicMin(&dmin_row[arow0 + row],
                      __float_as_uint(fmaxf(rmin0[r], 0.0f)));
            atomicMin(&dmin_row[arow0 + 32 + row],
                      __float_as_uint(fmaxf(rmin1[r], 0.0f)));
        }
    }

    // Col-side: plain coalesced stores to this x-block's private partial slab.
    __syncthreads();
    unsigned* dst = colpart + (size_t)blockIdx.x * NPTS + bbase;
    for (int i = tid; i < BSWEEP; i += BLOCK) dst[i] = scmin[i];
}

// Per-column min over the 64 x-block partials (coalesced, contention-free),
// fold in the row-side mins, block-reduce to 64 double partial sums.
__global__ __launch_bounds__(256) void merge_kernel(
    const unsigned* __restrict__ colpart, const unsigned* __restrict__ dmin_row,
    double* __restrict__ part)
{
    const int tid = threadIdx.x;
    const int c = blockIdx.x * 256 + tid;   // one column per thread
    unsigned m = 0x7F7F7F7Fu;
#pragma unroll
    for (int p = 0; p < NXB; ++p)
        m = min(m, colpart[(size_t)p * NPTS + c]);
    double s = (double)__uint_as_float(m) + (double)__uint_as_float(dmin_row[c]);

    __shared__ double sd[256];
    sd[tid] = s;
    __syncthreads();
    for (int off = 128; off > 0; off >>= 1) {
        if (tid < off) sd[tid] += sd[tid + off];
        __syncthreads();
    }
    if (tid == 0) part[blockIdx.x] = sd[0];
}

__global__ __launch_bounds__(64) void final_kernel(
    const double* __restrict__ part, float* __restrict__ out)
{
    __shared__ double sd[64];
    sd[threadIdx.x] = part[threadIdx.x];
    __syncthreads();
    for (int off = 32; off > 0; off >>= 1) {
        if (threadIdx.x < off) sd[threadIdx.x] += sd[threadIdx.x + off];
        __syncthreads();
    }
    // mean(dist0) + mean(dist1) = (sum_rows + sum_cols) / NPTS
    if (threadIdx.x == 0) out[0] = (float)(sd[0] / (double)NPTS);
}

extern "C" void kernel_launch(void* const* d_in, const int* in_sizes, int n_in,
                              void* d_out, int out_size, void* d_ws, size_t ws_size,
                              hipStream_t stream)
{
    const float* P0 = (const float*)d_in[0];
    const float* P1 = (const float*)d_in[1];
    float* out = (float*)d_out;

    char* ws = (char*)d_ws;
    unsigned* dmin_row = (unsigned*)ws;                       // 64 KB
    uint4* Ap = (uint4*)(ws + 64 * 1024);                     // 512 KB
    uint4* Bp = (uint4*)(ws + 576 * 1024);                    // 512 KB
    unsigned* colpart = (unsigned*)(ws + 1088 * 1024);        // 64*16384*4 = 4 MB
    double* part = (double*)(ws + 1088 * 1024 + 4 * 1024 * 1024);  // 512 B

    prep_kernel<<<(2 * NPTS) / 256, 256, 0, stream>>>(P0, P1, Ap, Bp, dmin_row);

    dim3 grid(NXB, NBSPLIT);   // 64 x 32 = 2048 blocks, 8 blocks/CU
    chamfer_mfma<<<grid, BLOCK, 0, stream>>>(Ap, Bp, dmin_row, colpart);

    merge_kernel<<<NPTS / 256, 256, 0, stream>>>(colpart, dmin_row, part);
    final_kernel<<<1, 64, 0, stream>>>(part, out);
}

// Round 18
// 33.348 us; speedup vs baseline: 1.4442x; 1.4442x over previous
//
#include <hip/hip_runtime.h>

// Chamfer (bidirectional 1-NN mean of squared distances), two [16384,3] fp32 clouds.
// Round-18: fuse + de-latency. R16 best (41.8) decomposed as ~4 nodes overhead +
// prep 2 + mfma ~27 (vs ~6us issue floor: latency on per-tile L2 loads + cold
// cross-XCD first pass) + merge 2.5 + final 1. Changes:
//  - prep FUSED into mfma kernel: A-frags computed in registers, B-slice frags
//    computed and staged to LDS (32KB, R7-verified [half][pt] layout) from raw
//    P0/P1 (L2-hot, ~15KB/block). ONE barrier; inner loop reads LDS only.
//  - ZERO atomics: row-mins stored to rowpart[by][row] slab (like colpart);
//    merge kernel min-reduces 64 col-partials + 16 row-partials per index.
//    No workspace init needed at all (every read slot written every call).
//  - NBSPLIT back to 16 (R17's 32 regressed: per-block overhead doubled).
// Inner-loop math byte-identical to R14/R16 (verified absmax 0.0, VGPR~64).
//
// MFMA formulation (one v_mfma_f32_32x32x16_f16 per 32x32 distance tile):
//   x = xh + xl (split fp16). K slots:
//     0..2 A=-2a_hi B=b_hi | 3..5 A=-2a_hi B=b_lo | 6..8 A=-2a_lo B=b_hi
//     9,10 A={a2_hi,a2_lo} B={1,1} | 11,12 A={1,1} B={b2_hi,b2_lo} | 13..15 zero
//   => D[i][j] = a2 + b2 - 2 a.b + O(3e-3), fp32 accumulators.
// C/D layout (verified): col=lane&31, row=(reg&3)+8*(reg>>2)+4*(lane>>5).

typedef _Float16 half8 __attribute__((ext_vector_type(8)));
typedef float floatx16 __attribute__((ext_vector_type(16)));

#define NPTS 16384
#define BLOCK 256
#define WAVES 4
#define TILE 32
#define ROWSW (2 * TILE)              // 64 A-rows per wave (2 fragments)
#define APB (WAVES * ROWSW)           // 256 A-points per block
#define NXB (NPTS / APB)              // 64 x-blocks (col-partial slabs)
#define NBSPLIT 16
#define BSWEEP (NPTS / NBSPLIT)       // 1024 B-points per block
#define NTILES (BSWEEP / TILE)        // 32 B-tiles per block

union H8 { _Float16 h[8]; uint4 u; };

// A-side fragment pair for one point (matches verified prep_kernel output).
__device__ inline void mk_afrag(float x, float y, float z, H8& a0, H8& a1) {
    const float q2 = x * x + y * y + z * z;
    const _Float16 xh = (_Float16)x; const float xl = x - (float)xh;
    const _Float16 yh = (_Float16)y; const float yl = y - (float)yh;
    const _Float16 zh = (_Float16)z; const float zl = z - (float)zh;
    const _Float16 qh = (_Float16)q2; const float ql = q2 - (float)qh;
    const _Float16 one = (_Float16)1.0f, zero = (_Float16)0.0f;
    a0.h[0] = (_Float16)(-2.0f * (float)xh);
    a0.h[1] = (_Float16)(-2.0f * (float)yh);
    a0.h[2] = (_Float16)(-2.0f * (float)zh);
    a0.h[3] = a0.h[0]; a0.h[4] = a0.h[1]; a0.h[5] = a0.h[2];
    a0.h[6] = (_Float16)(-2.0f * xl);
    a0.h[7] = (_Float16)(-2.0f * yl);
    a1.h[0] = (_Float16)(-2.0f * zl);
    a1.h[1] = qh; a1.h[2] = (_Float16)ql;
    a1.h[3] = one; a1.h[4] = one;
    a1.h[5] = zero; a1.h[6] = zero; a1.h[7] = zero;
}

// B-side fragment pair for one point (matches verified prep_kernel output).
__device__ inline void mk_bfrag(float x, float y, float z, H8& b0, H8& b1) {
    const float q2 = x * x + y * y + z * z;
    const _Float16 xh = (_Float16)x; const float xl = x - (float)xh;
    const _Float16 yh = (_Float16)y; const float yl = y - (float)yh;
    const _Float16 zh = (_Float16)z; const float zl = z - (float)zh;
    const _Float16 qh = (_Float16)q2; const float ql = q2 - (float)qh;
    const _Float16 one = (_Float16)1.0f, zero = (_Float16)0.0f;
    b0.h[0] = xh; b0.h[1] = yh; b0.h[2] = zh;
    b0.h[3] = (_Float16)xl; b0.h[4] = (_Float16)yl; b0.h[5] = (_Float16)zl;
    b0.h[6] = xh; b0.h[7] = yh;
    b1.h[0] = zh; b1.h[1] = one; b1.h[2] = one;
    b1.h[3] = qh; b1.h[4] = (_Float16)ql;
    b1.h[5] = zero; b1.h[6] = zero; b1.h[7] = zero;
}

#define MF(afx, bf) __builtin_amdgcn_mfma_f32_32x32x16_f16((afx), (bf), ZC, 0, 0, 0)

__global__ __launch_bounds__(BLOCK, 4) void chamfer_mfma(
    const float* __restrict__ P0, const float* __restrict__ P1,
    unsigned* __restrict__ rowpart, unsigned* __restrict__ colpart)
{
    __shared__ uint4 sB[2][BSWEEP];      // 32 KB B-fragment stage ([half][pt], R7 layout)
    __shared__ unsigned scmin[BSWEEP];   // 4 KB block col-min accumulator

    const int tid  = threadIdx.x;
    const int lane = tid & 63;
    const int wid  = tid >> 6;
    const int half = lane >> 5;
    const int lj   = lane & 31;

    const int bbase = blockIdx.y * BSWEEP;

    // Stage B-slice fragments: 4 points/thread from raw P1 (L2-hot), pre-split.
    for (int k = 0; k < BSWEEP / BLOCK; ++k) {
        const int p = tid + k * BLOCK;
        const int g = (bbase + p) * 3;
        H8 b0, b1;
        mk_bfrag(P1[g + 0], P1[g + 1], P1[g + 2], b0, b1);
        sB[0][p] = b0.u;
        sB[1][p] = b1.u;
        scmin[p % (BSWEEP)] = 0x7F7F7F7Fu;   // init col accumulator in same pass
    }

    // A fragments: 2 rows/lane from raw P0, computed in registers.
    const int arow0 = blockIdx.x * APB + wid * ROWSW;
    half8 af0, af1;
    {
        H8 a0, a1;
        const int g0 = (arow0 + lj) * 3;
        mk_afrag(P0[g0 + 0], P0[g0 + 1], P0[g0 + 2], a0, a1);
        const uint4 u0 = half ? a1.u : a0.u;
        af0 = *reinterpret_cast<const half8*>(&u0);
        const int g1 = (arow0 + 32 + lj) * 3;
        mk_afrag(P0[g1 + 0], P0[g1 + 1], P0[g1 + 2], a0, a1);
        const uint4 u1 = half ? a1.u : a0.u;
        af1 = *reinterpret_cast<const half8*>(&u1);
    }

    __syncthreads();   // single barrier: stage + init complete

    const floatx16 ZC = (floatx16)(0.0f);

    float rmin0[16], rmin1[16];
#pragma unroll
    for (int r = 0; r < 16; ++r) { rmin0[r] = 3.0e38f; rmin1[r] = 3.0e38f; }

    const uint4* myB = &sB[half][0];

    // Inner loop identical math to R14/R16 (verified); reads LDS only.
#pragma unroll 2
    for (int t = 0; t < NTILES; ++t) {
        const half8 bf = *reinterpret_cast<const half8*>(&myB[t * TILE + lj]);
        const floatx16 dA = MF(af0, bf);
        const floatx16 dB = MF(af1, bf);
#pragma unroll
        for (int r = 0; r < 16; ++r) {
            rmin0[r] = fminf(dA[r], rmin0[r]);
            rmin1[r] = fminf(dB[r], rmin1[r]);
        }
        float c = fminf(dA[0], dB[0]);
#pragma unroll
        for (int r = 1; r < 16; ++r) c = fminf(fminf(dA[r], dB[r]), c);
        c = fminf(c, __shfl_xor(c, 32, 64));
        if (lane < 32)
            atomicMin(&scmin[t * TILE + lj], __float_as_uint(fmaxf(c, 0.0f)));
    }

    // Row-side: butterfly, then plain stores to this y-block's row-partial slab.
#pragma unroll
    for (int r = 0; r < 16; ++r) {
        float v0 = rmin0[r];
        v0 = fminf(v0, __shfl_xor(v0, 1, 32));
        v0 = fminf(v0, __shfl_xor(v0, 2, 32));
        v0 = fminf(v0, __shfl_xor(v0, 4, 32));
        v0 = fminf(v0, __shfl_xor(v0, 8, 32));
        v0 = fminf(v0, __shfl_xor(v0, 16, 32));
        rmin0[r] = v0;
        float v1 = rmin1[r];
        v1 = fminf(v1, __shfl_xor(v1, 1, 32));
        v1 = fminf(v1, __shfl_xor(v1, 2, 32));
        v1 = fminf(v1, __shfl_xor(v1, 4, 32));
        v1 = fminf(v1, __shfl_xor(v1, 8, 32));
        v1 = fminf(v1, __shfl_xor(v1, 16, 32));
        rmin1[r] = v1;
    }
    if (lj == 0) {
        unsigned* rp = rowpart + (size_t)blockIdx.y * NPTS;
#pragma unroll
        for (int r = 0; r < 16; ++r) {
            const int row = (r & 3) + 8 * (r >> 2) + 4 * half;
            rp[arow0 + row]      = __float_as_uint(fmaxf(rmin0[r], 0.0f));
            rp[arow0 + 32 + row] = __float_as_uint(fmaxf(rmin1[r], 0.0f));
        }
    }

    // Col-side: plain coalesced stores to this x-block's col-partial slab.
    __syncthreads();
    unsigned* cp = colpart + (size_t)blockIdx.x * NPTS + bbase;
    for (int i = tid; i < BSWEEP; i += BLOCK) cp[i] = scmin[i];
}

// Per-index: min over 64 col-partials + min over 16 row-partials (all coalesced,
// contention-free); block-reduce to 64 double partial sums.
__global__ __launch_bounds__(256) void merge_kernel(
    const unsigned* __restrict__ colpart, const unsigned* __restrict__ rowpart,
    double* __restrict__ part)
{
    const int tid = threadIdx.x;
    const int c = blockIdx.x * 256 + tid;   // one row+col index per thread
    unsigned mc = 0x7F7F7F7Fu;
#pragma unroll
    for (int p = 0; p < NXB; ++p)
        mc = min(mc, colpart[(size_t)p * NPTS + c]);
    unsigned mr = 0x7F7F7F7Fu;
#pragma unroll
    for (int p = 0; p < NBSPLIT; ++p)
        mr = min(mr, rowpart[(size_t)p * NPTS + c]);
    double s = (double)__uint_as_float(mc) + (double)__uint_as_float(mr);

    __shared__ double sd[256];
    sd[tid] = s;
    __syncthreads();
    for (int off = 128; off > 0; off >>= 1) {
        if (tid < off) sd[tid] += sd[tid + off];
        __syncthreads();
    }
    if (tid == 0) part[blockIdx.x] = sd[0];
}

__global__ __launch_bounds__(64) void final_kernel(
    const double* __restrict__ part, float* __restrict__ out)
{
    __shared__ double sd[64];
    sd[threadIdx.x] = part[threadIdx.x];
    __syncthreads();
    for (int off = 32; off > 0; off >>= 1) {
        if (threadIdx.x < off) sd[threadIdx.x] += sd[threadIdx.x + off];
        __syncthreads();
    }
    // mean(dist0) + mean(dist1) = (sum_rows + sum_cols) / NPTS
    if (threadIdx.x == 0) out[0] = (float)(sd[0] / (double)NPTS);
}

extern "C" void kernel_launch(void* const* d_in, const int* in_sizes, int n_in,
                              void* d_out, int out_size, void* d_ws, size_t ws_size,
                              hipStream_t stream)
{
    const float* P0 = (const float*)d_in[0];
    const float* P1 = (const float*)d_in[1];
    float* out = (float*)d_out;

    char* ws = (char*)d_ws;
    unsigned* rowpart = (unsigned*)ws;                        // 16*16384*4 = 1 MB
    unsigned* colpart = (unsigned*)(ws + (1 << 20));          // 64*16384*4 = 4 MB
    double* part = (double*)(ws + (5 << 20));                 // 512 B

    dim3 grid(NXB, NBSPLIT);   // 64 x 16 = 1024 blocks, 4 blocks/CU
    chamfer_mfma<<<grid, BLOCK, 0, stream>>>(P0, P1, rowpart, colpart);

    merge_kernel<<<NPTS / 256, 256, 0, stream>>>(colpart, rowpart, part);
    final_kernel<<<1, 64, 0, stream>>>(part, out);
}